// Round 1
// baseline (1217.131 us; speedup 1.0000x reference)
//
#include <hip/hip_runtime.h>
#include <hip/hip_bf16.h>

// LightGCN forward: 3 propagation layers + layer mean.
// Strategy: build CSR (by dst) in workspace each call, then gather-based
// aggregation (no float atomics). One 32-lane group per node, lane = feature.

#define D 32

__global__ void deg_kernel(const int* __restrict__ dst, int E, int* __restrict__ deg) {
    int e = blockIdx.x * blockDim.x + threadIdx.x;
    if (e < E) atomicAdd(&deg[dst[e]], 1);
}

// --- exclusive scan over deg[0..n) -> row_ptr, plus rd = rsqrt(deg) ---
__global__ void scan_sum_kernel(const int* __restrict__ deg, int n, int* __restrict__ partials) {
    int idx = blockIdx.x * 1024 + threadIdx.x;
    int v = (idx < n) ? deg[idx] : 0;
    // reduce 1024 values: wave64 reduce then LDS across 16 waves
    for (int o = 32; o > 0; o >>= 1) v += __shfl_down(v, o, 64);
    __shared__ int sm[16];
    int wave = threadIdx.x >> 6;
    int lane = threadIdx.x & 63;
    if (lane == 0) sm[wave] = v;
    __syncthreads();
    if (threadIdx.x < 16) {
        int s = sm[threadIdx.x];
        for (int o = 8; o > 0; o >>= 1) s += __shfl_down(s, o, 16);
        if (threadIdx.x == 0) partials[blockIdx.x] = s;
    }
}

__global__ void scan_partials_kernel(int* __restrict__ partials, int nblk) {
    __shared__ int sm[1024];
    int t = threadIdx.x;
    int v = (t < nblk) ? partials[t] : 0;
    sm[t] = v;
    __syncthreads();
    for (int o = 1; o < 1024; o <<= 1) {
        int add = (t >= o) ? sm[t - o] : 0;
        __syncthreads();
        sm[t] += add;
        __syncthreads();
    }
    if (t < nblk) partials[t] = sm[t] - v;  // exclusive
}

__global__ void scan_write_kernel(const int* __restrict__ deg, int n, int E,
                                  const int* __restrict__ partials,
                                  int* __restrict__ row_ptr, float* __restrict__ rd) {
    __shared__ int sm[1024];
    int t = threadIdx.x;
    int idx = blockIdx.x * 1024 + t;
    int v = (idx < n) ? deg[idx] : 0;
    sm[t] = v;
    __syncthreads();
    for (int o = 1; o < 1024; o <<= 1) {
        int add = (t >= o) ? sm[t - o] : 0;
        __syncthreads();
        sm[t] += add;
        __syncthreads();
    }
    if (idx < n) {
        int excl = sm[t] - v + partials[blockIdx.x];
        row_ptr[idx] = excl;
        rd[idx] = (v > 0) ? rsqrtf((float)v) : 0.0f;
    }
    if (idx == 0) row_ptr[n] = E;
}

__global__ void fill_kernel(const int* __restrict__ src, const int* __restrict__ dst, int E,
                            const int* __restrict__ row_ptr, int* __restrict__ cnt,
                            int* __restrict__ col) {
    int e = blockIdx.x * blockDim.x + threadIdx.x;
    if (e < E) {
        int dd = dst[e];
        int pos = row_ptr[dd] + atomicAdd(&cnt[dd], 1);
        col[pos] = src[e];
    }
}

__global__ void init_kernel(const float* __restrict__ ue, const float* __restrict__ ie,
                            int nu32, int tot32, float* __restrict__ x, float* __restrict__ acc) {
    int i = blockIdx.x * blockDim.x + threadIdx.x;
    if (i < tot32) {
        float v = (i < nu32) ? ue[i] : ie[i - nu32];
        x[i] = v;
        acc[i] = 0.25f * v;   // layer-0 term of the mean, pre-scaled by 1/(L+1)
    }
}

// One 32-lane group per node; lane = feature index f.
// x_next[i][f] = rd[i] * sum_{e in row i} rd[col[e]] * x_cur[col[e]][f]
__global__ void layer_kernel(const int* __restrict__ row_ptr, const int* __restrict__ col,
                             const float* __restrict__ rd, const float* __restrict__ xin,
                             float* __restrict__ xout, float* __restrict__ acc, int n) {
    int gid = blockIdx.x * blockDim.x + threadIdx.x;
    int node = gid >> 5;
    int f = gid & 31;
    if (node >= n) return;
    int e0 = row_ptr[node];
    int e1 = row_ptr[node + 1];
    float s = 0.0f;
    for (int base = e0; base < e1; base += 32) {
        int idx = base + f;
        int c = 0;
        float r = 0.0f;
        if (idx < e1) {          // cooperative 32-wide load of neighbor ids + their rd
            c = col[idx];
            r = rd[c];
        }
        int cnt = min(32, e1 - base);
        for (int j = 0; j < cnt; ++j) {
            int   cj = __shfl(c, j, 32);
            float rj = __shfl(r, j, 32);
            s += rj * xin[cj * D + f];   // 128B coalesced line per neighbor
        }
    }
    float val = rd[node] * s;
    xout[node * D + f] = val;
    acc[node * D + f] += 0.25f * val;
}

extern "C" void kernel_launch(void* const* d_in, const int* in_sizes, int n_in,
                              void* d_out, int out_size, void* d_ws, size_t ws_size,
                              hipStream_t stream) {
    const int*   edge = (const int*)d_in[0];
    const float* ue   = (const float*)d_in[3];
    const float* ie   = (const float*)d_in[4];
    int E  = in_sizes[0] / 2;
    int nu = in_sizes[3] / D;
    int ni = in_sizes[4] / D;
    int n  = nu + ni;
    const int* src = edge;
    const int* dst = edge + E;
    float* out = (float*)d_out;

    // workspace layout (~102 MB)
    char* p = (char*)d_ws;
    int*   deg      = (int*)p;  p += (size_t)n * 4;
    int*   cnt      = (int*)p;  p += (size_t)n * 4;
    int*   row_ptr  = (int*)p;  p += (size_t)(n + 1) * 4;
    int*   partials = (int*)p;  p += 4096 * 4;
    float* rd       = (float*)p; p += (size_t)n * 4;
    int*   col      = (int*)p;  p += (size_t)E * 4;
    float* xa       = (float*)p; p += (size_t)n * D * 4;
    float* xb       = (float*)p; p += (size_t)n * D * 4;

    hipMemsetAsync(deg, 0, (size_t)n * 4, stream);
    hipMemsetAsync(cnt, 0, (size_t)n * 4, stream);

    deg_kernel<<<(E + 255) / 256, 256, 0, stream>>>(dst, E, deg);

    int nblk = (n + 1023) / 1024;   // 293 for n=300k (must be <= 1024)
    scan_sum_kernel<<<nblk, 1024, 0, stream>>>(deg, n, partials);
    scan_partials_kernel<<<1, 1024, 0, stream>>>(partials, nblk);
    scan_write_kernel<<<nblk, 1024, 0, stream>>>(deg, n, E, partials, row_ptr, rd);

    fill_kernel<<<(E + 255) / 256, 256, 0, stream>>>(src, dst, E, row_ptr, cnt, col);

    int tot32 = n * D;
    init_kernel<<<(tot32 + 255) / 256, 256, 0, stream>>>(ue, ie, nu * D, tot32, xa, out);

    float* xin = xa;
    float* xout = xb;
    for (int l = 0; l < 3; ++l) {
        layer_kernel<<<(tot32 + 255) / 256, 256, 0, stream>>>(row_ptr, col, rd, xin, xout, out, n);
        float* t = xin; xin = xout; xout = t;
    }
}